// Round 2
// baseline (377.194 us; speedup 1.0000x reference)
//
#include <hip/hip_runtime.h>

#define B_SZ 2
#define S_LEN 2048
#define HID_DIM 2048
#define NHEADS 16
#define HEAD_D 128
#define WIN 1024
#define M_ROWS (B_SZ * S_LEN)

typedef __attribute__((ext_vector_type(8))) short bf16x8;
typedef __attribute__((ext_vector_type(4))) float f32x4;

#define SCALE_F 0.08838834764831845f   /* 1/sqrt(128) */
#define SOFTCAP_F 30.0f

__device__ __forceinline__ unsigned short f2bf(float f) {
  unsigned u = __builtin_bit_cast(unsigned, f);
  unsigned r = (u + 0x7FFFu + ((u >> 16) & 1u)) >> 16;
  return (unsigned short)r;
}

// ---------------- fp32 -> bf16 conversion (8 elems/thread) ----------------
__global__ __launch_bounds__(256) void cvt_bf16_kernel(const float* __restrict__ in,
                                                       unsigned short* __restrict__ out,
                                                       int n8) {
  int i = blockIdx.x * 256 + threadIdx.x;
  if (i >= n8) return;
  const f32x4* p = (const f32x4*)in + (size_t)i * 2;
  f32x4 a = p[0], b = p[1];
  bf16x8 o;
  o[0] = (short)f2bf(a[0]); o[1] = (short)f2bf(a[1]);
  o[2] = (short)f2bf(a[2]); o[3] = (short)f2bf(a[3]);
  o[4] = (short)f2bf(b[0]); o[5] = (short)f2bf(b[1]);
  o[6] = (short)f2bf(b[2]); o[7] = (short)f2bf(b[3]);
  *((bf16x8*)out + i) = o;
}

// ---------------- async global->LDS 16B ----------------
__device__ __forceinline__ void gload16(const unsigned short* g, unsigned short* l) {
  __builtin_amdgcn_global_load_lds(
      (const __attribute__((address_space(1))) unsigned int*)g,
      (__attribute__((address_space(3))) unsigned int*)l, 16, 0, 0);
}

// ---------------- bf16 GEMM, C = A * B^T (A:[M,K], B:[N,K] row-major) -----
// m97 structure: 128x128 tile, BK=32, 4 waves (2x2), 16x16x32 MFMA.
template <bool F32OUT>
__global__ __launch_bounds__(256, 2)
void gemm_bt_kernel(const unsigned short* __restrict__ A,
                    const unsigned short* __restrict__ Bm,
                    void* __restrict__ Cp, int M, int N, int K) {
  __shared__ unsigned short sA[128 * 32];
  __shared__ unsigned short sB[128 * 32];
  const int t = threadIdx.x;
  const int l = t & 63;
  const int w = t >> 6;
  const int g = l >> 4, c = l & 15;
  const int wr = w >> 1, wc = w & 1;
  const int m0 = blockIdx.y * 128, n0 = blockIdx.x * 128;

  f32x4 acc[4][4];
#pragma unroll
  for (int i = 0; i < 4; ++i)
#pragma unroll
    for (int j = 0; j < 4; ++j) acc[i][j] = (f32x4)0.0f;

  for (int k0 = 0; k0 < K; k0 += 32) {
#pragma unroll
    for (int i = 0; i < 2; ++i) {
      int li = i * 256 + t;
      int row = li >> 2, seg = li & 3;
      gload16(A + (size_t)(m0 + row) * K + k0 + seg * 8, &sA[li * 8]);
      gload16(Bm + (size_t)(n0 + row) * K + k0 + seg * 8, &sB[li * 8]);
    }
    __syncthreads();
    bf16x8 af[4], bfr[4];
#pragma unroll
    for (int mi = 0; mi < 4; ++mi)
      af[mi] = *(const bf16x8*)&sA[(wr * 64 + mi * 16 + c) * 32 + g * 8];
#pragma unroll
    for (int ni = 0; ni < 4; ++ni)
      bfr[ni] = *(const bf16x8*)&sB[(wc * 64 + ni * 16 + c) * 32 + g * 8];
#pragma unroll
    for (int mi = 0; mi < 4; ++mi)
#pragma unroll
      for (int ni = 0; ni < 4; ++ni)
        acc[mi][ni] = __builtin_amdgcn_mfma_f32_16x16x32_bf16(af[mi], bfr[ni],
                                                              acc[mi][ni], 0, 0, 0);
    __syncthreads();
  }

  // epilogue: C row = (lane>>4)*4 + reg, col = lane&15 (guide-verified m89/m91)
#pragma unroll
  for (int mi = 0; mi < 4; ++mi)
#pragma unroll
    for (int ni = 0; ni < 4; ++ni)
#pragma unroll
      for (int r = 0; r < 4; ++r) {
        int row = m0 + wr * 64 + mi * 16 + g * 4 + r;
        int col = n0 + wc * 64 + ni * 16 + c;
        if (F32OUT)
          ((float*)Cp)[(size_t)row * N + col] = acc[mi][ni][r];
        else
          ((unsigned short*)Cp)[(size_t)row * N + col] = f2bf(acc[mi][ni][r]);
      }
}

// ---------------- flash attention, sliding-window causal + softcap --------
// grid: (S/64, B*H). block: 256 (4 waves x 16 q-rows). KV tile = 32 keys.
// Softcap bounds |score| <= 30, so we use a FIXED softmax max of 30:
// p = ok ? exp(s-30) : 0. No online max, no rescale, no masked-row hazard.
__global__ __launch_bounds__(256, 2)
void attn_kernel(const unsigned short* __restrict__ Qb,
                 const unsigned short* __restrict__ Kb,
                 const unsigned short* __restrict__ Vb,
                 unsigned short* __restrict__ Ob) {
  __shared__ unsigned short K_lds[32 * HEAD_D];  // swizzled ^((row&7)<<3) (elem)
  __shared__ unsigned short V_lds[32 * HEAD_D];  // swizzled ^((((k>>3)&3)<<4)|((k&3)<<3))
  __shared__ unsigned short P_lds[4][16 * 40];   // per-wave P, stride 40 elems

  const int t = threadIdx.x;
  const int w = t >> 6, l = t & 63;
  const int g = l >> 4, c = l & 15;
  const int q0 = blockIdx.x * 64;
  const int bh = blockIdx.y;
  const int b = bh >> 4, h = bh & 15;
  const size_t base = (size_t)b * S_LEN * HID_DIM + (size_t)h * HEAD_D;
  const int qw = q0 + w * 16;

  // preload Q fragments for this wave's 16 rows
  bf16x8 qf[4];
  {
    const unsigned short* qp = Qb + base + (size_t)(qw + c) * HID_DIM + g * 8;
#pragma unroll
    for (int dch = 0; dch < 4; ++dch) qf[dch] = *(const bf16x8*)(qp + dch * 32);
  }

  f32x4 acc[8];
#pragma unroll
  for (int dc = 0; dc < 8; ++dc) acc[dc] = (f32x4)0.0f;
  float lrow[4] = {0.0f, 0.0f, 0.0f, 0.0f};

  int kstart = q0 - (WIN - 1);
  if (kstart < 0) kstart = 0;
  kstart &= ~31;
  const int kend = q0 + 63;

  for (int k0 = kstart; k0 <= kend; k0 += 32) {
    // ---- stage K,V tile (reg path so we can swizzle) ----
#pragma unroll
    for (int i = 0; i < 2; ++i) {
      int li = i * 256 + t;
      int row = li >> 4, ch = li & 15;
      const unsigned short* kg = Kb + base + (size_t)(k0 + row) * HID_DIM + ch * 8;
      const unsigned short* vg = Vb + base + (size_t)(k0 + row) * HID_DIM + ch * 8;
      bf16x8 kv = *(const bf16x8*)kg;
      bf16x8 vv = *(const bf16x8*)vg;
      int ke = (row * HEAD_D + ch * 8) ^ ((row & 7) << 3);
      int ve = (row * HEAD_D + ch * 8) ^ ((((row >> 3) & 3) << 4) | ((row & 3) << 3));
      *(bf16x8*)&K_lds[ke] = kv;
      *(bf16x8*)&V_lds[ve] = vv;
    }
    __syncthreads();

    bool active = !(k0 > qw + 15 || k0 + 31 < qw - (WIN - 1));
    if (active) {
      // ---- QK^T: scores [16q x 32k], two 16-key halves ----
      f32x4 sc[2];
      sc[0] = (f32x4)0.0f; sc[1] = (f32x4)0.0f;
#pragma unroll
      for (int kc = 0; kc < 2; ++kc) {
#pragma unroll
        for (int dch = 0; dch < 4; ++dch) {
          int row = kc * 16 + c;
          int e = (row * HEAD_D + dch * 32 + g * 8) ^ ((row & 7) << 3);
          bf16x8 kf = *(const bf16x8*)&K_lds[e];
          sc[kc] = __builtin_amdgcn_mfma_f32_16x16x32_bf16(qf[dch], kf, sc[kc], 0, 0, 0);
        }
      }
      // ---- softcap + mask + fixed-max exp ----
      float p[2][4];
#pragma unroll
      for (int kc = 0; kc < 2; ++kc)
#pragma unroll
        for (int r = 0; r < 4; ++r) {
          int i_g = qw + g * 4 + r;
          int j_g = k0 + kc * 16 + c;
          float y = sc[kc][r] * (SCALE_F / SOFTCAP_F);
          float e2 = __expf(-2.0f * fabsf(y));
          float th = (1.0f - e2) / (1.0f + e2);
          float s = SOFTCAP_F * copysignf(th, y);
          bool ok = (j_g <= i_g) && (i_g - j_g < WIN);
          p[kc][r] = ok ? __expf(s - SOFTCAP_F) : 0.0f;
        }
      // ---- denominator accumulation (row-sum across 16 lanes of group) ----
#pragma unroll
      for (int r = 0; r < 4; ++r) {
        float rs = p[0][r] + p[1][r];
#pragma unroll
        for (int msk = 1; msk < 16; msk <<= 1) rs += __shfl_xor(rs, msk);
        lrow[r] += rs;
      }
      // ---- P -> LDS (A-fragment layout round trip) ----
#pragma unroll
      for (int kc = 0; kc < 2; ++kc)
#pragma unroll
        for (int r = 0; r < 4; ++r)
          P_lds[w][(g * 4 + r) * 40 + kc * 16 + c] = f2bf(p[kc][r]);
      bf16x8 pa = *(const bf16x8*)&P_lds[w][c * 40 + g * 8];
      // ---- PV: acc[16q x 128d] += P * V ----
#pragma unroll
      for (int dc = 0; dc < 8; ++dc) {
        bf16x8 vf;
#pragma unroll
        for (int j = 0; j < 8; ++j) {
          int k = g * 8 + j;
          int d = dc * 16 + c;
          int e = (k * HEAD_D + d) ^ ((((k >> 3) & 3) << 4) | ((k & 3) << 3));
          vf[j] = (short)V_lds[e];
        }
        acc[dc] = __builtin_amdgcn_mfma_f32_16x16x32_bf16(pa, vf, acc[dc], 0, 0, 0);
      }
    }
    __syncthreads();
  }

  // ---- epilogue: normalize and store bf16 [B,S,H,D] ----
#pragma unroll
  for (int dc = 0; dc < 8; ++dc)
#pragma unroll
    for (int r = 0; r < 4; ++r) {
      int q = qw + g * 4 + r;
      float o = acc[dc][r] / lrow[r];
      Ob[base + (size_t)q * HID_DIM + dc * 16 + c] = f2bf(o);
    }
}

// ---------------- host launch ----------------
extern "C" void kernel_launch(void* const* d_in, const int* in_sizes, int n_in,
                              void* d_out, int out_size, void* d_ws, size_t ws_size,
                              hipStream_t stream) {
  const float* x  = (const float*)d_in[0];
  const float* Wq = (const float*)d_in[1];
  const float* Wk = (const float*)d_in[2];
  const float* Wv = (const float*)d_in[3];
  const float* Wo = (const float*)d_in[4];

  const size_t NX = (size_t)M_ROWS * HID_DIM;    // 8,388,608
  const size_t NW = (size_t)HID_DIM * HID_DIM;   // 4,194,304

  unsigned short* xb  = (unsigned short*)d_ws;
  unsigned short* Wqb = xb + NX;
  unsigned short* Wkb = Wqb + NW;
  unsigned short* Wvb = Wkb + NW;
  unsigned short* Wob = Wvb + NW;
  unsigned short* Qb  = Wob + NW;
  unsigned short* Kb  = Qb + NX;
  unsigned short* Vb  = Kb + NX;
  unsigned short* Ab  = xb;  // reuse x_bf16 region for attn output

  // 1) convert inputs to bf16
  cvt_bf16_kernel<<<dim3((unsigned)(NX / 8 / 256)), 256, 0, stream>>>(x, xb, (int)(NX / 8));
  cvt_bf16_kernel<<<dim3((unsigned)(NW / 8 / 256)), 256, 0, stream>>>(Wq, Wqb, (int)(NW / 8));
  cvt_bf16_kernel<<<dim3((unsigned)(NW / 8 / 256)), 256, 0, stream>>>(Wk, Wkb, (int)(NW / 8));
  cvt_bf16_kernel<<<dim3((unsigned)(NW / 8 / 256)), 256, 0, stream>>>(Wv, Wvb, (int)(NW / 8));
  cvt_bf16_kernel<<<dim3((unsigned)(NW / 8 / 256)), 256, 0, stream>>>(Wo, Wob, (int)(NW / 8));

  // 2) QKV projections (bf16 out, [B,S,H,D] layout)
  dim3 ggrid(HID_DIM / 128, M_ROWS / 128);
  gemm_bt_kernel<false><<<ggrid, 256, 0, stream>>>(xb, Wqb, Qb, M_ROWS, HID_DIM, HID_DIM);
  gemm_bt_kernel<false><<<ggrid, 256, 0, stream>>>(xb, Wkb, Kb, M_ROWS, HID_DIM, HID_DIM);
  gemm_bt_kernel<false><<<ggrid, 256, 0, stream>>>(xb, Wvb, Vb, M_ROWS, HID_DIM, HID_DIM);

  // 3) attention
  attn_kernel<<<dim3(S_LEN / 64, B_SZ * NHEADS), 256, 0, stream>>>(Qb, Kb, Vb, Ab);

  // 4) output projection (fp32 out)
  gemm_bt_kernel<true><<<ggrid, 256, 0, stream>>>(Ab, Wob, d_out, M_ROWS, HID_DIM, HID_DIM);
}